// Round 1
// baseline (2586.159 us; speedup 1.0000x reference)
//
#include <hip/hip_runtime.h>

#define TS 64
#define TKDIM 16

// ---------- helpers: order-preserving float<->key for radix select ----------
__device__ __forceinline__ unsigned f2k(float f){
  unsigned u = __float_as_uint(f);
  return (u & 0x80000000u) ? ~u : (u | 0x80000000u);
}
__device__ __forceinline__ float k2f(unsigned k){
  unsigned u = (k & 0x80000000u) ? (k & 0x7fffffffu) : ~k;
  return __uint_as_float(u);
}

// ---------- generic tiled f32 GEMM, C = alpha * A(MxK) @ B(KxN) [+ bias] ----------
// A row-major stride lda, B row-major stride ldb, C row-major stride ldc.
// grid = (N/64, M/64), block = 256. All dims multiples of tile sizes.
__global__ __launch_bounds__(256) void gemm_nn(
    const float* __restrict__ A, int lda,
    const float* __restrict__ B, int ldb,
    float* __restrict__ C, int ldc,
    int K, float alpha, const float* __restrict__ bias)
{
  __shared__ __align__(16) float As[TKDIM][TS+4];
  __shared__ __align__(16) float Bs[TKDIM][TS+4];
  const int t = threadIdx.x;
  const int tx = t & 15, ty = t >> 4;
  const size_t row0 = (size_t)blockIdx.y * TS, col0 = (size_t)blockIdx.x * TS;
  const int ka = t & 15, ma = t >> 4;   // A staging: k = ka, m = ma + 16*i
  const int nb = t & 63, kb = t >> 6;   // B staging: n = nb, k = kb + 4*i
  const float* Ap = A + row0 * lda;
  const float* Bp = B + col0;
  float acc[4][4] = {};
  for (int k0 = 0; k0 < K; k0 += TKDIM){
    #pragma unroll
    for (int i = 0; i < 4; i++)
      As[ka][ma + 16*i] = Ap[(size_t)(ma + 16*i) * lda + (k0 + ka)];
    #pragma unroll
    for (int i = 0; i < 4; i++)
      Bs[kb + 4*i][nb] = Bp[(size_t)(k0 + kb + 4*i) * ldb + nb];
    __syncthreads();
    #pragma unroll
    for (int kk = 0; kk < TKDIM; kk++){
      float4 a4 = *(const float4*)&As[kk][ty*4];
      float4 b4 = *(const float4*)&Bs[kk][tx*4];
      const float av[4] = {a4.x, a4.y, a4.z, a4.w};
      const float bv[4] = {b4.x, b4.y, b4.z, b4.w};
      #pragma unroll
      for (int i = 0; i < 4; i++)
        #pragma unroll
        for (int j = 0; j < 4; j++)
          acc[i][j] = fmaf(av[i], bv[j], acc[i][j]);
    }
    __syncthreads();
  }
  #pragma unroll
  for (int i = 0; i < 4; i++){
    size_t r = row0 + ty*4 + i;
    size_t c = col0 + tx*4;
    float4 v;
    float* vp = (float*)&v;
    #pragma unroll
    for (int j = 0; j < 4; j++){
      float val = acc[i][j] * alpha;
      if (bias) val += bias[c + j];
      vp[j] = val;
    }
    *(float4*)&C[r*ldc + c] = v;
  }
}

// ---------- NT GEMM: C = alpha * A(MxK) @ B(NxK)^T  (for QK^T scores) ----------
__global__ __launch_bounds__(256) void gemm_nt(
    const float* __restrict__ A, int lda,
    const float* __restrict__ B, int ldb,   // B is N x K row-major
    float* __restrict__ C, int ldc,
    int K, float alpha)
{
  __shared__ __align__(16) float As[TKDIM][TS+4];
  __shared__ __align__(16) float Bs[TKDIM][TS+4];
  const int t = threadIdx.x;
  const int tx = t & 15, ty = t >> 4;
  const size_t row0 = (size_t)blockIdx.y * TS, col0 = (size_t)blockIdx.x * TS;
  const int ka = t & 15, ma = t >> 4;
  const float* Ap = A + row0 * lda;
  const float* Bp = B + col0 * ldb;
  float acc[4][4] = {};
  for (int k0 = 0; k0 < K; k0 += TKDIM){
    #pragma unroll
    for (int i = 0; i < 4; i++)
      As[ka][ma + 16*i] = Ap[(size_t)(ma + 16*i) * lda + (k0 + ka)];
    #pragma unroll
    for (int i = 0; i < 4; i++)
      Bs[ka][ma + 16*i] = Bp[(size_t)(ma + 16*i) * ldb + (k0 + ka)];
    __syncthreads();
    #pragma unroll
    for (int kk = 0; kk < TKDIM; kk++){
      float4 a4 = *(const float4*)&As[kk][ty*4];
      float4 b4 = *(const float4*)&Bs[kk][tx*4];
      const float av[4] = {a4.x, a4.y, a4.z, a4.w};
      const float bv[4] = {b4.x, b4.y, b4.z, b4.w};
      #pragma unroll
      for (int i = 0; i < 4; i++)
        #pragma unroll
        for (int j = 0; j < 4; j++)
          acc[i][j] = fmaf(av[i], bv[j], acc[i][j]);
    }
    __syncthreads();
  }
  #pragma unroll
  for (int i = 0; i < 4; i++){
    size_t r = row0 + ty*4 + i;
    size_t c = col0 + tx*4;
    float4 v;
    float* vp = (float*)&v;
    #pragma unroll
    for (int j = 0; j < 4; j++) vp[j] = acc[i][j] * alpha;
    *(float4*)&C[r*ldc + c] = v;
  }
}

// ---------- plain row softmax over 4096 cols, one block per row ----------
__global__ __launch_bounds__(256) void softmax_row4096(float* __restrict__ sc){
  __shared__ float buf[4096];
  __shared__ float red[4];
  __shared__ float red2[4];
  const int t = threadIdx.x;
  float* p = sc + (size_t)blockIdx.x * 4096;
  float m = -3.0e38f;
  for (int i = t; i < 4096; i += 256){ float v = p[i]; buf[i] = v; m = fmaxf(m, v); }
  #pragma unroll
  for (int off = 32; off; off >>= 1) m = fmaxf(m, __shfl_xor(m, off));
  if ((t & 63) == 0) red[t >> 6] = m;
  __syncthreads();
  m = fmaxf(fmaxf(red[0], red[1]), fmaxf(red[2], red[3]));
  float s = 0.f;
  for (int i = t; i < 4096; i += 256){ float e = expf(buf[i] - m); buf[i] = e; s += e; }
  #pragma unroll
  for (int off = 32; off; off >>= 1) s += __shfl_xor(s, off);
  if ((t & 63) == 0) red2[t >> 6] = s;
  __syncthreads();
  s = red2[0] + red2[1] + red2[2] + red2[3];
  float inv = 1.0f / s;
  for (int i = t; i < 4096; i += 256) p[i] = buf[i] * inv;
}

// ---------- exact top-k (radix select) + masked softmax, one block per row ----------
__global__ __launch_bounds__(256) void sparse_softmax4096(float* __restrict__ sc, int ksel){
  __shared__ unsigned keys[4096];
  __shared__ unsigned hist[256];
  __shared__ unsigned suf[256];
  __shared__ int selb;
  __shared__ float redf[4];
  __shared__ float redf2[4];
  const int t = threadIdx.x;
  float* p = sc + (size_t)blockIdx.x * 4096;

  float m = -3.0e38f;
  for (int i = t; i < 4096; i += 256){ float v = p[i]; keys[i] = f2k(v); m = fmaxf(m, v); }
  #pragma unroll
  for (int off = 32; off; off >>= 1) m = fmaxf(m, __shfl_xor(m, off));
  if ((t & 63) == 0) redf[t >> 6] = m;
  __syncthreads();
  m = fmaxf(fmaxf(redf[0], redf[1]), fmaxf(redf[2], redf[3]));

  unsigned prefix = 0;
  unsigned remaining = (unsigned)ksel;
  for (int pass = 0; pass < 4; ++pass){
    const int shift = 24 - 8*pass;
    hist[t] = 0u;
    __syncthreads();
    for (int i = t; i < 4096; i += 256){
      unsigned k = keys[i];
      bool cand = (pass == 0) || ((k >> (shift + 8)) == prefix);
      if (cand) atomicAdd(&hist[(k >> shift) & 255u], 1u);
    }
    __syncthreads();
    suf[t] = hist[t];
    __syncthreads();
    for (int off = 1; off < 256; off <<= 1){
      unsigned add = (t + off < 256) ? suf[t + off] : 0u;
      __syncthreads();
      suf[t] += add;
      __syncthreads();
    }
    if (suf[t] >= remaining && (t == 255 || suf[t+1] < remaining)) selb = t;
    __syncthreads();
    int b = selb;
    remaining -= (b == 255) ? 0u : suf[b+1];
    prefix = (prefix << 8) | (unsigned)b;
    __syncthreads();
  }
  const unsigned Tkey = prefix;  // exact key of the ksel-th largest value

  float s = 0.f;
  for (int i = t; i < 4096; i += 256){
    unsigned k = keys[i];
    if (k >= Tkey) s += expf(k2f(k) - m);
  }
  #pragma unroll
  for (int off = 32; off; off >>= 1) s += __shfl_xor(s, off);
  if ((t & 63) == 0) redf2[t >> 6] = s;
  __syncthreads();
  s = redf2[0] + redf2[1] + redf2[2] + redf2[3];
  float inv = 1.0f / s;
  for (int i = t; i < 4096; i += 256){
    unsigned k = keys[i];
    p[i] = (k >= Tkey) ? expf(k2f(k) - m) * inv : 0.0f;
  }
}

// ---------- memory head: scores vs 64-slot bank, softmax, retrieve ----------
// cat is [8192][512]: cols 0:256 hold x_proj (input), cols 256:512 get retrieved.
__global__ __launch_bounds__(256) void memory_head(float* __restrict__ cat,
                                                   const float* __restrict__ bank){
  __shared__ float xp[256];
  __shared__ float w[64];
  const int t = threadIdx.x;
  for (int r = 0; r < 8; r++){
    const size_t row = (size_t)blockIdx.x * 8 + r;
    __syncthreads();
    xp[t] = cat[row*512 + t];
    __syncthreads();
    if (t < 64){
      const float* br = bank + (size_t)t * 256;
      float sv = 0.f;
      for (int h = 0; h < 256; h++) sv = fmaf(xp[h], br[h], sv);
      float mx = sv;
      #pragma unroll
      for (int off = 32; off; off >>= 1) mx = fmaxf(mx, __shfl_xor(mx, off));
      float e = expf(sv - mx);
      float sum = e;
      #pragma unroll
      for (int off = 32; off; off >>= 1) sum += __shfl_xor(sum, off);
      w[t] = e / sum;
    }
    __syncthreads();
    float rr = 0.f;
    for (int m2 = 0; m2 < 64; m2++) rr = fmaf(w[m2], bank[(size_t)m2*256 + t], rr);
    cat[row*512 + 256 + t] = rr;
  }
}

// ---------- exact GELU ----------
__global__ __launch_bounds__(256) void gelu_k(float* __restrict__ h, int n){
  int i = blockIdx.x * 256 + threadIdx.x;
  const int stride = gridDim.x * 256;
  for (; i < n; i += stride){
    float v = h[i];
    h[i] = 0.5f * v * (1.0f + erff(v * 0.70710678118654752f));
  }
}

extern "C" void kernel_launch(void* const* d_in, const int* in_sizes, int n_in,
                              void* d_out, int out_size, void* d_ws, size_t ws_size,
                              hipStream_t stream)
{
  const float* x             = (const float*)d_in[0];
  const float* local_qkv_w   = (const float*)d_in[1];
  const float* sparse_qkv_w  = (const float*)d_in[2];
  const float* memory_bank   = (const float*)d_in[3];
  const float* memory_proj_w = (const float*)d_in[4];
  const float* mem_out_w     = (const float*)d_in[5];
  const float* mem_out_b     = (const float*)d_in[6];
  const float* pred_in_w     = (const float*)d_in[7];
  const float* pred_in_b     = (const float*)d_in[8];
  const float* pred1_w       = (const float*)d_in[9];
  const float* pred1_b       = (const float*)d_in[10];
  const float* pred2_w       = (const float*)d_in[11];
  const float* pred2_b       = (const float*)d_in[12];
  const float* warboss_w     = (const float*)d_in[13];
  const float* warboss_b     = (const float*)d_in[14];
  float* out = (float*)d_out;

  // workspace layout (floats): qkv[8192*768] | scores[4096*4096] | combined[8192*1024]
  // scores region is reused (stream-ordered) by mem_cat / h_in / h1 after attention.
  float* ws       = (float*)d_ws;
  float* qkv      = ws;                       // 6,291,456 floats
  float* scores   = ws + 6291456;             // 16,777,216 floats
  float* combined = ws + 23068672;            // 8,388,608 floats
  float* mem_cat  = scores;                   // 8192*512
  float* h_in     = scores + 4194304;         // 8192*256
  float* h1       = h_in + 2097152;           // 8192*512

  const dim3 blk(256);
  const float scale = 0.0625f;  // 256^-0.5

  // ---- local (full) attention -> combined[:, 0:256] ----
  gemm_nn<<<dim3(12,128), blk, 0, stream>>>(x, 1024, local_qkv_w, 768, qkv, 768, 1024, 1.f, nullptr);
  for (int b = 0; b < 2; b++){
    const float* Q = qkv + (size_t)b * 4096 * 768;
    gemm_nt<<<dim3(64,64), blk, 0, stream>>>(Q, 768, Q + 256, 768, scores, 4096, 256, scale);
    softmax_row4096<<<dim3(4096), blk, 0, stream>>>(scores);
    gemm_nn<<<dim3(4,64), blk, 0, stream>>>(scores, 4096, Q + 512, 768,
                                            combined + (size_t)b * 4096 * 1024, 1024, 4096, 1.f, nullptr);
  }

  // ---- sparse (top-k) attention -> combined[:, 256:512] ----
  gemm_nn<<<dim3(12,128), blk, 0, stream>>>(x, 1024, sparse_qkv_w, 768, qkv, 768, 1024, 1.f, nullptr);
  for (int b = 0; b < 2; b++){
    const float* Q = qkv + (size_t)b * 4096 * 768;
    gemm_nt<<<dim3(64,64), blk, 0, stream>>>(Q, 768, Q + 256, 768, scores, 4096, 256, scale);
    sparse_softmax4096<<<dim3(4096), blk, 0, stream>>>(scores, 409);  // int(4096*0.1)
    gemm_nn<<<dim3(4,64), blk, 0, stream>>>(scores, 4096, Q + 512, 768,
                                            combined + (size_t)b * 4096 * 1024 + 256, 1024, 4096, 1.f, nullptr);
  }

  // ---- memory head -> combined[:, 512:768] ----
  gemm_nn<<<dim3(4,128), blk, 0, stream>>>(x, 1024, memory_proj_w, 256, mem_cat, 512, 1024, 1.f, nullptr);
  memory_head<<<dim3(1024), blk, 0, stream>>>(mem_cat, memory_bank);
  gemm_nn<<<dim3(4,128), blk, 0, stream>>>(mem_cat, 512, mem_out_w, 256, combined + 512, 1024, 512, 1.f, mem_out_b);

  // ---- prediction head -> combined[:, 768:1024] ----
  gemm_nn<<<dim3(4,128), blk, 0, stream>>>(x, 1024, pred_in_w, 256, h_in, 256, 1024, 1.f, pred_in_b);
  gemm_nn<<<dim3(8,128), blk, 0, stream>>>(h_in, 256, pred1_w, 512, h1, 512, 256, 1.f, pred1_b);
  gelu_k<<<dim3(2048), blk, 0, stream>>>(h1, 4194304);
  gemm_nn<<<dim3(4,128), blk, 0, stream>>>(h1, 512, pred2_w, 256, combined + 768, 1024, 512, 1.f, pred2_b);

  // ---- output projection ----
  gemm_nn<<<dim3(16,128), blk, 0, stream>>>(combined, 1024, warboss_w, 1024, out, 1024, 1024, 1.f, warboss_b);
}

// Round 3
// 765.459 us; speedup vs baseline: 3.3786x; 3.3786x over previous
//
#include <hip/hip_runtime.h>
#include <hip/hip_bf16.h>

typedef __attribute__((ext_vector_type(8))) _Float16 half8;
typedef __attribute__((ext_vector_type(4))) float f32x4;

__device__ __forceinline__ float wred_max(float v){
  #pragma unroll
  for (int o = 32; o; o >>= 1) v = fmaxf(v, __shfl_xor(v, o));
  return v;
}
__device__ __forceinline__ float wred_sum(float v){
  #pragma unroll
  for (int o = 32; o; o >>= 1) v += __shfl_xor(v, o);
  return v;
}
__device__ __forceinline__ unsigned f2k(float f){
  unsigned u = __float_as_uint(f);
  return (u & 0x80000000u) ? ~u : (u | 0x80000000u);
}

#define GLOAD16(GP, LP) __builtin_amdgcn_global_load_lds( \
    (const __attribute__((address_space(1))) void*)(GP),  \
    (__attribute__((address_space(3))) void*)(LP), 16, 0, 0)

// ======== MFMA GEMM (f16 in, f32 acc): C = alpha * A(MxK) @ B(NxK)^T (+bias) ========
// OUT_F16: 1 -> _Float16 C, 0 -> f32 C. ACT=1 -> exact GELU after bias.
// grid = (N/BN, M/BM); block = 256 (4 waves, 2x2 wave tiles).
template<int BM, int BN, int OUT_F16, int ACT>
__global__ __launch_bounds__(256) void gemm_ht(
    const _Float16* __restrict__ A, int lda,
    const _Float16* __restrict__ B, int ldb,
    void* __restrict__ Cv, int ldc,
    int K, float alpha, const float* __restrict__ bias)
{
  constexpr int FM = BM / 32, FN = BN / 32;
  __shared__ __align__(16) _Float16 Asl[BM * 32];
  __shared__ __align__(16) _Float16 Bsl[BN * 32];
  const int t = threadIdx.x;
  const int wid = t >> 6, lane = t & 63;
  const int wr = wid >> 1, wc = wid & 1;
  const int lr = lane & 15, kg = lane >> 4;
  const long row0 = (long)blockIdx.y * BM;
  const long col0 = (long)blockIdx.x * BN;

  f32x4 acc[FM][FN];
  #pragma unroll
  for (int i = 0; i < FM; i++)
    #pragma unroll
    for (int j = 0; j < FN; j++)
      acc[i][j] = (f32x4){0.f, 0.f, 0.f, 0.f};

  const int arow_t = t >> 2, acol_t = (t & 3) * 8;

  for (int k0 = 0; k0 < K; k0 += 32){
    #pragma unroll
    for (int r = 0; r < BM / 64; r++){
      const _Float16* gp = A + (row0 + r*64 + arow_t) * (long)lda + k0 + acol_t;
      GLOAD16(gp, (char*)Asl + r*4096 + wid*1024);
    }
    #pragma unroll
    for (int r = 0; r < BN / 64; r++){
      const _Float16* gp = B + (col0 + r*64 + arow_t) * (long)ldb + k0 + acol_t;
      GLOAD16(gp, (char*)Bsl + r*4096 + wid*1024);
    }
    __syncthreads();
    half8 af[FM], bfv[FN];
    #pragma unroll
    for (int i = 0; i < FM; i++)
      af[i] = *(const half8*)((const char*)Asl + (wr*(BM/2) + i*16 + lr)*64 + kg*16);
    #pragma unroll
    for (int j = 0; j < FN; j++)
      bfv[j] = *(const half8*)((const char*)Bsl + (wc*(BN/2) + j*16 + lr)*64 + kg*16);
    #pragma unroll
    for (int i = 0; i < FM; i++)
      #pragma unroll
      for (int j = 0; j < FN; j++)
        acc[i][j] = __builtin_amdgcn_mfma_f32_16x16x32_f16(af[i], bfv[j], acc[i][j], 0, 0, 0);
    __syncthreads();
  }

  _Float16* Ch = (_Float16*)Cv;
  float*    Cf = (float*)Cv;
  #pragma unroll
  for (int i = 0; i < FM; i++){
    #pragma unroll
    for (int j = 0; j < FN; j++){
      #pragma unroll
      for (int q = 0; q < 4; q++){
        long rr = row0 + wr*(BM/2) + i*16 + kg*4 + q;
        long cc = col0 + wc*(BN/2) + j*16 + lr;
        float val = acc[i][j][q] * alpha;
        if (bias) val += bias[cc];
        if constexpr (ACT) val = 0.5f * val * (1.0f + erff(val * 0.70710678118654752f));
        if constexpr (OUT_F16) Ch[rr*(long)ldc + cc] = (_Float16)val;
        else                   Cf[rr*(long)ldc + cc] = val;
      }
    }
  }
}

// ======== cast f32 -> f16 (8 elems/thread) ========
__global__ __launch_bounds__(256) void cast_xh(const float* __restrict__ in,
                                               _Float16* __restrict__ out, int n8){
  int i = blockIdx.x * 256 + threadIdx.x;
  const int stride = gridDim.x * 256;
  for (; i < n8; i += stride){
    float4 a = ((const float4*)in)[2*i];
    float4 b = ((const float4*)in)[2*i + 1];
    half8 o;
    o[0]=(_Float16)a.x; o[1]=(_Float16)a.y; o[2]=(_Float16)a.z; o[3]=(_Float16)a.w;
    o[4]=(_Float16)b.x; o[5]=(_Float16)b.y; o[6]=(_Float16)b.z; o[7]=(_Float16)b.w;
    *(half8*)(out + (size_t)i*8) = o;
  }
}

// ======== transpose+cast weight: in (R x C) f32 -> out (C x R) f16 ========
__global__ __launch_bounds__(256) void transpose_cast_w(const float* __restrict__ in, int R, int C,
                                                        _Float16* __restrict__ out){
  __shared__ float tile[32][33];
  const int c0 = blockIdx.x * 32, r0 = blockIdx.y * 32;
  const int tx = threadIdx.x & 31, ty = threadIdx.x >> 5;
  #pragma unroll
  for (int i = 0; i < 32; i += 8)
    tile[ty+i][tx] = in[(size_t)(r0+ty+i)*C + c0+tx];
  __syncthreads();
  #pragma unroll
  for (int i = 0; i < 32; i += 8)
    out[(size_t)(c0+ty+i)*R + r0+tx] = (_Float16)tile[tx][ty+i];
}

// ======== f16 transpose: in (R x C, ld_in) -> out (C x R, ld_out), z-batched ========
__global__ __launch_bounds__(256) void transpose_h(
    const _Float16* __restrict__ in, long in_z, int ld_in,
    _Float16* __restrict__ out, long out_z, int ld_out)
{
  __shared__ _Float16 tile[32][34];
  const _Float16* ip = in + (long)blockIdx.z * in_z;
  _Float16* op = out + (long)blockIdx.z * out_z;
  const int c0 = blockIdx.x * 32, r0 = blockIdx.y * 32;
  const int tx = threadIdx.x & 31, ty = threadIdx.x >> 5;
  #pragma unroll
  for (int i = 0; i < 32; i += 8)
    tile[ty+i][tx] = ip[(long)(r0+ty+i)*ld_in + c0+tx];
  __syncthreads();
  #pragma unroll
  for (int i = 0; i < 32; i += 8)
    op[(long)(c0+ty+i)*ld_out + r0+tx] = tile[tx][ty+i];
}

// ======== full softmax: read f32 row (4096), write f16 probs IN PLACE ========
// probs row occupies first 8192 bytes of each 16384-byte f32 row.
__global__ __launch_bounds__(256) void softmax_inplace(float* __restrict__ sc){
  __shared__ float red[4], red2[4];
  const int t = threadIdx.x, lane = t & 63, wid = t >> 6;
  float* p = sc + (size_t)blockIdx.x * 4096;
  float v[16];
  #pragma unroll
  for (int j = 0; j < 4; j++){
    float4 q = *(const float4*)(p + t*16 + j*4);
    v[4*j] = q.x; v[4*j+1] = q.y; v[4*j+2] = q.z; v[4*j+3] = q.w;
  }
  float m = v[0];
  #pragma unroll
  for (int e = 1; e < 16; e++) m = fmaxf(m, v[e]);
  m = wred_max(m);
  if (lane == 0) red[wid] = m;
  __syncthreads();
  m = fmaxf(fmaxf(red[0], red[1]), fmaxf(red[2], red[3]));
  float s = 0.f;
  #pragma unroll
  for (int e = 0; e < 16; e++){ v[e] = expf(v[e] - m); s += v[e]; }
  s = wred_sum(s);
  if (lane == 0) red2[wid] = s;
  __syncthreads();
  s = red2[0] + red2[1] + red2[2] + red2[3];
  const float inv = 1.0f / s;
  _Float16* ph = (_Float16*)p;
  half8 o0, o1;
  #pragma unroll
  for (int e = 0; e < 8; e++){ o0[e] = (_Float16)(v[e]*inv); o1[e] = (_Float16)(v[8+e]*inv); }
  *(half8*)(ph + t*16)     = o0;
  *(half8*)(ph + t*16 + 8) = o1;
}

// ======== exact top-k (4x8-bit radix on f32 keys) + masked softmax, f16 in place ========
__global__ __launch_bounds__(256) void sparse_softmax_inplace(float* __restrict__ sc, int ksel){
  __shared__ unsigned hist[256];
  __shared__ unsigned suf[256];
  __shared__ int selb;
  __shared__ float red[4], red2[4];
  const int t = threadIdx.x, lane = t & 63, wid = t >> 6;
  float* p = sc + (size_t)blockIdx.x * 4096;
  float v[16]; unsigned kk[16];
  #pragma unroll
  for (int j = 0; j < 4; j++){
    float4 q = *(const float4*)(p + t*16 + j*4);
    v[4*j] = q.x; v[4*j+1] = q.y; v[4*j+2] = q.z; v[4*j+3] = q.w;
  }
  #pragma unroll
  for (int e = 0; e < 16; e++) kk[e] = f2k(v[e]);
  float m = v[0];
  #pragma unroll
  for (int e = 1; e < 16; e++) m = fmaxf(m, v[e]);
  m = wred_max(m);
  if (lane == 0) red[wid] = m;
  __syncthreads();
  m = fmaxf(fmaxf(red[0], red[1]), fmaxf(red[2], red[3]));

  unsigned prefix = 0;
  unsigned remaining = (unsigned)ksel;
  for (int pass = 0; pass < 4; ++pass){
    const int shift = 24 - 8*pass;
    hist[t] = 0u;
    __syncthreads();
    #pragma unroll
    for (int e = 0; e < 16; e++){
      unsigned k = kk[e];
      bool cand = (pass == 0) || ((k >> (shift + 8)) == prefix);
      if (cand) atomicAdd(&hist[(k >> shift) & 255u], 1u);
    }
    __syncthreads();
    suf[t] = hist[t];
    __syncthreads();
    for (int off = 1; off < 256; off <<= 1){
      unsigned add = (t + off < 256) ? suf[t + off] : 0u;
      __syncthreads();
      suf[t] += add;
      __syncthreads();
    }
    if (suf[t] >= remaining && (t == 255 || suf[t+1] < remaining)) selb = t;
    __syncthreads();
    int b = selb;
    remaining -= (b == 255) ? 0u : suf[b+1];
    prefix = (prefix << 8) | (unsigned)b;
    __syncthreads();
  }
  const unsigned Tkey = prefix;  // exact key of the ksel-th largest score

  float ev[16];
  float s = 0.f;
  #pragma unroll
  for (int e = 0; e < 16; e++){
    ev[e] = (kk[e] >= Tkey) ? expf(v[e] - m) : 0.f;
    s += ev[e];
  }
  s = wred_sum(s);
  if (lane == 0) red2[wid] = s;
  __syncthreads();
  s = red2[0] + red2[1] + red2[2] + red2[3];
  const float inv = 1.0f / s;
  _Float16* ph = (_Float16*)p;
  half8 o0, o1;
  #pragma unroll
  for (int e = 0; e < 8; e++){
    o0[e] = (_Float16)(ev[e]   * inv);
    o1[e] = (_Float16)(ev[8+e] * inv);
  }
  *(half8*)(ph + t*16)     = o0;
  *(half8*)(ph + t*16 + 8) = o1;
}

// ======== memory head: scores vs 64-slot bank (f32), softmax, retrieve (f16 cat) ========
__global__ __launch_bounds__(256) void memory_head_h(_Float16* __restrict__ cat,
                                                     const float* __restrict__ bank){
  __shared__ float xp[256];
  __shared__ float w[64];
  const int t = threadIdx.x;
  for (int r = 0; r < 8; r++){
    const size_t row = (size_t)blockIdx.x * 8 + r;
    __syncthreads();
    xp[t] = (float)cat[row*512 + t];
    __syncthreads();
    if (t < 64){
      const float* br = bank + (size_t)t * 256;
      float sv = 0.f;
      for (int h = 0; h < 256; h++) sv = fmaf(xp[h], br[h], sv);
      float mx = sv;
      #pragma unroll
      for (int off = 32; off; off >>= 1) mx = fmaxf(mx, __shfl_xor(mx, off));
      float e = expf(sv - mx);
      float sum = e;
      #pragma unroll
      for (int off = 32; off; off >>= 1) sum += __shfl_xor(sum, off);
      w[t] = e / sum;
    }
    __syncthreads();
    float rr = 0.f;
    for (int m2 = 0; m2 < 64; m2++) rr = fmaf(w[m2], bank[(size_t)m2*256 + t], rr);
    cat[row*512 + 256 + t] = (_Float16)rr;
  }
}

extern "C" void kernel_launch(void* const* d_in, const int* in_sizes, int n_in,
                              void* d_out, int out_size, void* d_ws, size_t ws_size,
                              hipStream_t stream)
{
  const float* x             = (const float*)d_in[0];
  const float* local_qkv_w   = (const float*)d_in[1];
  const float* sparse_qkv_w  = (const float*)d_in[2];
  const float* memory_bank   = (const float*)d_in[3];
  const float* memory_proj_w = (const float*)d_in[4];
  const float* mem_out_w     = (const float*)d_in[5];
  const float* mem_out_b     = (const float*)d_in[6];
  const float* pred_in_w     = (const float*)d_in[7];
  const float* pred_in_b     = (const float*)d_in[8];
  const float* pred1_w       = (const float*)d_in[9];
  const float* pred1_b       = (const float*)d_in[10];
  const float* pred2_w       = (const float*)d_in[11];
  const float* pred2_b       = (const float*)d_in[12];
  const float* warboss_w     = (const float*)d_in[13];
  const float* warboss_b     = (const float*)d_in[14];
  float* out = (float*)d_out;

  // ---- workspace layout (bytes).
  // Region A [0, 64MB+3MB): f32 scores [4096][4096] for ONE batch (67,108,864 B).
  // Aliases (all consumed before the first score GEMM):
  //   x_h  f16 [8192][1024] @ 0          (16.78 MB)
  //   mem_cat f16 [8192][512] @ 16777216 (8.39 MB)
  //   h_in f16 [8192][256]  @ 25165824   (4.19 MB)
  //   h1   f16 [8192][512]  @ 29360128   (8.39 MB)
  char* wsb = (char*)d_ws;
  float*     scores  = (float*)wsb;
  _Float16*  x_h     = (_Float16*)wsb;
  _Float16*  mem_cat = (_Float16*)(wsb + 16777216);
  _Float16*  h_in    = (_Float16*)(wsb + 25165824);
  _Float16*  h1      = (_Float16*)(wsb + 29360128);
  _Float16*  qkv_l   = (_Float16*)(wsb + 67108864);   // [8192][768]
  _Float16*  qkv_s   = (_Float16*)(wsb + 79691776);   // [8192][768]
  _Float16*  Vt      = (_Float16*)(wsb + 92274688);   // [2][256][4096]
  _Float16*  comb    = (_Float16*)(wsb + 96468992);   // [8192][1024]
  _Float16*  lqkvT   = (_Float16*)(wsb + 113246208);  // [768][1024]
  _Float16*  sqkvT   = lqkvT  + 786432;
  _Float16*  mprojT  = sqkvT  + 786432;               // [256][1024]
  _Float16*  moutT   = mprojT + 262144;               // [256][512]
  _Float16*  pinT    = moutT  + 131072;               // [256][1024]
  _Float16*  p1T     = pinT   + 262144;               // [512][256]
  _Float16*  p2T     = p1T    + 131072;               // [256][512]
  _Float16*  wbT     = p2T    + 131072;               // [1024][1024]

  const dim3 blk(256);
  const float scale = 0.0625f;
  const long QZ = (long)4096 * 768;
  const long VZ = (long)256 * 4096;
  const long CZ = (long)4096 * 1024;

  // ---- casts / weight transposes ----
  cast_xh<<<dim3(2048), blk, 0, stream>>>(x, x_h, 1048576);
  transpose_cast_w<<<dim3(24,32), blk, 0, stream>>>(local_qkv_w,  1024,  768, lqkvT);
  transpose_cast_w<<<dim3(24,32), blk, 0, stream>>>(sparse_qkv_w, 1024,  768, sqkvT);
  transpose_cast_w<<<dim3( 8,32), blk, 0, stream>>>(memory_proj_w,1024,  256, mprojT);
  transpose_cast_w<<<dim3( 8,16), blk, 0, stream>>>(mem_out_w,     512,  256, moutT);
  transpose_cast_w<<<dim3( 8,32), blk, 0, stream>>>(pred_in_w,    1024,  256, pinT);
  transpose_cast_w<<<dim3(16, 8), blk, 0, stream>>>(pred1_w,       256,  512, p1T);
  transpose_cast_w<<<dim3( 8,16), blk, 0, stream>>>(pred2_w,       512,  256, p2T);
  transpose_cast_w<<<dim3(32,32), blk, 0, stream>>>(warboss_w,    1024, 1024, wbT);

  // ---- QKV projections ----
  gemm_ht<128,128,1,0><<<dim3(6,64), blk, 0, stream>>>(x_h,1024, lqkvT,1024, qkv_l,768, 1024, 1.f, nullptr);
  gemm_ht<128,128,1,0><<<dim3(6,64), blk, 0, stream>>>(x_h,1024, sqkvT,1024, qkv_s,768, 1024, 1.f, nullptr);

  // ---- memory + prediction heads (consume region-A aliases before score GEMMs) ----
  gemm_ht<128,64,1,0><<<dim3(4,64), blk, 0, stream>>>(x_h,1024, mprojT,1024, mem_cat,512, 1024, 1.f, nullptr);
  memory_head_h<<<dim3(1024), blk, 0, stream>>>(mem_cat, memory_bank);
  gemm_ht<128,64,1,0><<<dim3(4,64), blk, 0, stream>>>(mem_cat,512, moutT,512, comb+512,1024, 512, 1.f, mem_out_b);
  gemm_ht<128,64,1,0><<<dim3(4,64), blk, 0, stream>>>(x_h,1024, pinT,1024, h_in,256, 1024, 1.f, pred_in_b);
  gemm_ht<128,128,1,1><<<dim3(4,64), blk, 0, stream>>>(h_in,256, p1T,256, h1,512, 256, 1.f, pred1_b);
  gemm_ht<128,64,1,0><<<dim3(4,64), blk, 0, stream>>>(h1,512, p2T,512, comb+768,1024, 512, 1.f, pred2_b);

  // ---- V transposes for both attentions' PV (Vt reused local->sparse) ----
  transpose_h<<<dim3(8,128,2), blk, 0, stream>>>(qkv_l+512, QZ, 768, Vt, VZ, 4096);

  // ---- local (full) attention -> comb[:, 0:256], one batch at a time ----
  for (int b = 0; b < 2; b++){
    const _Float16* Q = qkv_l + (long)b * QZ;
    gemm_ht<128,128,0,0><<<dim3(32,32), blk, 0, stream>>>(Q,768, Q+256,768, (void*)scores,4096, 256, scale, nullptr);
    softmax_inplace<<<dim3(4096), blk, 0, stream>>>(scores);
    gemm_ht<128,64,1,0><<<dim3(4,32), blk, 0, stream>>>((const _Float16*)scores,8192, Vt + (long)b*VZ,4096,
                                                        comb + (long)b*CZ, 1024, 4096, 1.f, nullptr);
  }

  // ---- sparse (top-k) attention -> comb[:, 256:512] ----
  transpose_h<<<dim3(8,128,2), blk, 0, stream>>>(qkv_s+512, QZ, 768, Vt, VZ, 4096);
  for (int b = 0; b < 2; b++){
    const _Float16* Q = qkv_s + (long)b * QZ;
    gemm_ht<128,128,0,0><<<dim3(32,32), blk, 0, stream>>>(Q,768, Q+256,768, (void*)scores,4096, 256, scale, nullptr);
    sparse_softmax_inplace<<<dim3(4096), blk, 0, stream>>>(scores, 409);
    gemm_ht<128,64,1,0><<<dim3(4,32), blk, 0, stream>>>((const _Float16*)scores,8192, Vt + (long)b*VZ,4096,
                                                        comb + (long)b*CZ + 256, 1024, 4096, 1.f, nullptr);
  }

  // ---- output projection (f32 out) ----
  gemm_ht<128,128,0,0><<<dim3(8,64), blk, 0, stream>>>(comb,1024, wbT,1024, (void*)out,1024, 1024, 1.f, warboss_b);
}

// Round 4
// 564.498 us; speedup vs baseline: 4.5813x; 1.3560x over previous
//
#include <hip/hip_runtime.h>
#include <hip/hip_bf16.h>

typedef __attribute__((ext_vector_type(8))) _Float16 half8;
typedef __attribute__((ext_vector_type(4))) _Float16 half4v;
typedef __attribute__((ext_vector_type(4))) float f32x4;

__device__ __forceinline__ float wred_max(float v){
  #pragma unroll
  for (int o = 32; o; o >>= 1) v = fmaxf(v, __shfl_xor(v, o));
  return v;
}
__device__ __forceinline__ float wred_sum(float v){
  #pragma unroll
  for (int o = 32; o; o >>= 1) v += __shfl_xor(v, o);
  return v;
}
__device__ __forceinline__ unsigned f2k(float f){
  unsigned u = __float_as_uint(f);
  return (u & 0x80000000u) ? ~u : (u | 0x80000000u);
}

#define GLOAD16(GP, LP) __builtin_amdgcn_global_load_lds( \
    (const __attribute__((address_space(1))) void*)(GP),  \
    (__attribute__((address_space(3))) void*)(LP), 16, 0, 0)

// ======== MFMA GEMM (f16 in, f32 acc): C = alpha * A(MxK) @ B(NxK)^T (+bias) ========
// z-batched via saz/sbz/scz element strides. OUT_F16: 1 -> f16 C, 0 -> f32 C. ACT=1 -> exact GELU.
template<int BM, int BN, int OUT_F16, int ACT>
__global__ __launch_bounds__(256) void gemm_ht(
    const _Float16* __restrict__ A, long saz, int lda,
    const _Float16* __restrict__ B, long sbz, int ldb,
    void* __restrict__ Cv, long scz, int ldc,
    int K, float alpha, const float* __restrict__ bias)
{
  constexpr int FM = BM / 32, FN = BN / 32;
  __shared__ __align__(16) _Float16 Asl[BM * 32];
  __shared__ __align__(16) _Float16 Bsl[BN * 32];
  const int t = threadIdx.x;
  const int wid = t >> 6, lane = t & 63;
  const int wr = wid >> 1, wc = wid & 1;
  const int lr = lane & 15, kg = lane >> 4;
  A += (long)blockIdx.z * saz;
  B += (long)blockIdx.z * sbz;
  const long row0 = (long)blockIdx.y * BM;
  const long col0 = (long)blockIdx.x * BN;

  f32x4 acc[FM][FN];
  #pragma unroll
  for (int i = 0; i < FM; i++)
    #pragma unroll
    for (int j = 0; j < FN; j++)
      acc[i][j] = (f32x4){0.f, 0.f, 0.f, 0.f};

  const int arow_t = t >> 2, acol_t = (t & 3) * 8;

  for (int k0 = 0; k0 < K; k0 += 32){
    #pragma unroll
    for (int r = 0; r < BM / 64; r++){
      const _Float16* gp = A + (row0 + r*64 + arow_t) * (long)lda + k0 + acol_t;
      GLOAD16(gp, (char*)Asl + r*4096 + wid*1024);
    }
    #pragma unroll
    for (int r = 0; r < BN / 64; r++){
      const _Float16* gp = B + (col0 + r*64 + arow_t) * (long)ldb + k0 + acol_t;
      GLOAD16(gp, (char*)Bsl + r*4096 + wid*1024);
    }
    __syncthreads();
    half8 af[FM], bfv[FN];
    #pragma unroll
    for (int i = 0; i < FM; i++)
      af[i] = *(const half8*)((const char*)Asl + (wr*(BM/2) + i*16 + lr)*64 + kg*16);
    #pragma unroll
    for (int j = 0; j < FN; j++)
      bfv[j] = *(const half8*)((const char*)Bsl + (wc*(BN/2) + j*16 + lr)*64 + kg*16);
    #pragma unroll
    for (int i = 0; i < FM; i++)
      #pragma unroll
      for (int j = 0; j < FN; j++)
        acc[i][j] = __builtin_amdgcn_mfma_f32_16x16x32_f16(af[i], bfv[j], acc[i][j], 0, 0, 0);
    __syncthreads();
  }

  _Float16* Ch = (_Float16*)Cv + (long)blockIdx.z * scz;
  float*    Cf = (float*)Cv    + (long)blockIdx.z * scz;
  #pragma unroll
  for (int i = 0; i < FM; i++){
    #pragma unroll
    for (int j = 0; j < FN; j++){
      #pragma unroll
      for (int q = 0; q < 4; q++){
        long rr = row0 + wr*(BM/2) + i*16 + kg*4 + q;
        long cc = col0 + wc*(BN/2) + j*16 + lr;
        float val = acc[i][j][q] * alpha;
        if (bias) val += bias[cc];
        if constexpr (ACT) val = 0.5f * val * (1.0f + erff(val * 0.70710678118654752f));
        if constexpr (OUT_F16) Ch[rr*(long)ldc + cc] = (_Float16)val;
        else                   Cf[rr*(long)ldc + cc] = val;
      }
    }
  }
}

// ======== split-K PV GEMM: partial = A(4096xKsplit) @ B(256xKsplit)^T, f32 partials ========
// z = batch*nsplit + split; partial block z lives at P + z*4096*256.
template<int BM, int BN>
__global__ __launch_bounds__(256) void gemm_pv(
    const _Float16* __restrict__ A, long saz, int lda,
    const _Float16* __restrict__ B, long sbz, int ldb,
    float* __restrict__ P, int nsplit, int Ksplit)
{
  constexpr int FM = BM / 32, FN = BN / 32;
  __shared__ __align__(16) _Float16 Asl[BM * 32];
  __shared__ __align__(16) _Float16 Bsl[BN * 32];
  const int t = threadIdx.x;
  const int wid = t >> 6, lane = t & 63;
  const int wr = wid >> 1, wc = wid & 1;
  const int lr = lane & 15, kg = lane >> 4;
  const int z = blockIdx.z, batch = z / nsplit, split = z % nsplit;
  A += (long)batch * saz;
  B += (long)batch * sbz;
  float* Pz = P + (size_t)z * (4096 * 256);
  const long row0 = (long)blockIdx.y * BM;
  const long col0 = (long)blockIdx.x * BN;
  const int Kbase = split * Ksplit;

  f32x4 acc[FM][FN];
  #pragma unroll
  for (int i = 0; i < FM; i++)
    #pragma unroll
    for (int j = 0; j < FN; j++)
      acc[i][j] = (f32x4){0.f, 0.f, 0.f, 0.f};

  const int arow_t = t >> 2, acol_t = (t & 3) * 8;

  for (int k0 = 0; k0 < Ksplit; k0 += 32){
    #pragma unroll
    for (int r = 0; r < BM / 64; r++){
      const _Float16* gp = A + (row0 + r*64 + arow_t) * (long)lda + Kbase + k0 + acol_t;
      GLOAD16(gp, (char*)Asl + r*4096 + wid*1024);
    }
    #pragma unroll
    for (int r = 0; r < BN / 64; r++){
      const _Float16* gp = B + (col0 + r*64 + arow_t) * (long)ldb + Kbase + k0 + acol_t;
      GLOAD16(gp, (char*)Bsl + r*4096 + wid*1024);
    }
    __syncthreads();
    half8 af[FM], bfv[FN];
    #pragma unroll
    for (int i = 0; i < FM; i++)
      af[i] = *(const half8*)((const char*)Asl + (wr*(BM/2) + i*16 + lr)*64 + kg*16);
    #pragma unroll
    for (int j = 0; j < FN; j++)
      bfv[j] = *(const half8*)((const char*)Bsl + (wc*(BN/2) + j*16 + lr)*64 + kg*16);
    #pragma unroll
    for (int i = 0; i < FM; i++)
      #pragma unroll
      for (int j = 0; j < FN; j++)
        acc[i][j] = __builtin_amdgcn_mfma_f32_16x16x32_f16(af[i], bfv[j], acc[i][j], 0, 0, 0);
    __syncthreads();
  }

  #pragma unroll
  for (int i = 0; i < FM; i++)
    #pragma unroll
    for (int j = 0; j < FN; j++)
      #pragma unroll
      for (int q = 0; q < 4; q++){
        long rr = row0 + wr*(BM/2) + i*16 + kg*4 + q;
        long cc = col0 + wc*(BN/2) + j*16 + lr;
        Pz[rr*256 + cc] = acc[i][j][q];
      }
}

// ======== sum 4 split-K partials -> f16 into comb at column offset ========
// i indexes float4 positions; b = i>>18 selects the batch group (4 partials each).
__global__ __launch_bounds__(256) void reduce4(const float* __restrict__ P,
                                               _Float16* __restrict__ dst, int coff, int nq){
  int i = blockIdx.x * 256 + threadIdx.x;
  if (i >= nq) return;
  int b = i >> 18;
  int r = i & 262143;
  int row = r >> 6, col4 = r & 63;
  const float4* P4 = (const float4*)P;
  float4 s = P4[(size_t)(b*4 + 0) * 262144 + r];
  #pragma unroll
  for (int sp = 1; sp < 4; sp++){
    float4 q = P4[(size_t)(b*4 + sp) * 262144 + r];
    s.x += q.x; s.y += q.y; s.z += q.z; s.w += q.w;
  }
  half4v o;
  o[0] = (_Float16)s.x; o[1] = (_Float16)s.y; o[2] = (_Float16)s.z; o[3] = (_Float16)s.w;
  *(half4v*)(dst + ((size_t)b*4096 + row)*1024 + coff + col4*4) = o;
}

// ======== cast f32 -> f16 (8 elems/thread) ========
__global__ __launch_bounds__(256) void cast_xh(const float* __restrict__ in,
                                               _Float16* __restrict__ out, int n8){
  int i = blockIdx.x * 256 + threadIdx.x;
  const int stride = gridDim.x * 256;
  for (; i < n8; i += stride){
    float4 a = ((const float4*)in)[2*i];
    float4 b = ((const float4*)in)[2*i + 1];
    half8 o;
    o[0]=(_Float16)a.x; o[1]=(_Float16)a.y; o[2]=(_Float16)a.z; o[3]=(_Float16)a.w;
    o[4]=(_Float16)b.x; o[5]=(_Float16)b.y; o[6]=(_Float16)b.z; o[7]=(_Float16)b.w;
    *(half8*)(out + (size_t)i*8) = o;
  }
}

// ======== transpose+cast weight: in (R x C) f32 -> out (C x R) f16 ========
__global__ __launch_bounds__(256) void transpose_cast_w(const float* __restrict__ in, int R, int C,
                                                        _Float16* __restrict__ out){
  __shared__ float tile[32][33];
  const int c0 = blockIdx.x * 32, r0 = blockIdx.y * 32;
  const int tx = threadIdx.x & 31, ty = threadIdx.x >> 5;
  #pragma unroll
  for (int i = 0; i < 32; i += 8)
    tile[ty+i][tx] = in[(size_t)(r0+ty+i)*C + c0+tx];
  __syncthreads();
  #pragma unroll
  for (int i = 0; i < 32; i += 8)
    out[(size_t)(c0+ty+i)*R + r0+tx] = (_Float16)tile[tx][ty+i];
}

// ======== f16 transpose: in (R x C, ld_in) -> out (C x R, ld_out), z-batched ========
__global__ __launch_bounds__(256) void transpose_h(
    const _Float16* __restrict__ in, long in_z, int ld_in,
    _Float16* __restrict__ out, long out_z, int ld_out)
{
  __shared__ _Float16 tile[32][34];
  const _Float16* ip = in + (long)blockIdx.z * in_z;
  _Float16* op = out + (long)blockIdx.z * out_z;
  const int c0 = blockIdx.x * 32, r0 = blockIdx.y * 32;
  const int tx = threadIdx.x & 31, ty = threadIdx.x >> 5;
  #pragma unroll
  for (int i = 0; i < 32; i += 8)
    tile[ty+i][tx] = ip[(long)(r0+ty+i)*ld_in + c0+tx];
  __syncthreads();
  #pragma unroll
  for (int i = 0; i < 32; i += 8)
    op[(long)(c0+ty+i)*ld_out + r0+tx] = tile[tx][ty+i];
}

// ======== full softmax over a 4096-wide f16 row, in place (local head) ========
__global__ __launch_bounds__(256) void softmax_f16row(_Float16* __restrict__ sc){
  __shared__ float red[4], red2[4];
  const int t = threadIdx.x, lane = t & 63, wid = t >> 6;
  _Float16* p = sc + (size_t)blockIdx.x * 4096;
  half8 a = ((const half8*)p)[t*2];
  half8 b = ((const half8*)p)[t*2 + 1];
  float v[16];
  #pragma unroll
  for (int e = 0; e < 8; e++){ v[e] = (float)a[e]; v[8+e] = (float)b[e]; }
  float m = v[0];
  #pragma unroll
  for (int e = 1; e < 16; e++) m = fmaxf(m, v[e]);
  m = wred_max(m);
  if (lane == 0) red[wid] = m;
  __syncthreads();
  m = fmaxf(fmaxf(red[0], red[1]), fmaxf(red[2], red[3]));
  float s = 0.f;
  #pragma unroll
  for (int e = 0; e < 16; e++){ v[e] = expf(v[e] - m); s += v[e]; }
  s = wred_sum(s);
  if (lane == 0) red2[wid] = s;
  __syncthreads();
  s = red2[0] + red2[1] + red2[2] + red2[3];
  const float inv = 1.0f / s;
  half8 oa, ob;
  #pragma unroll
  for (int e = 0; e < 8; e++){ oa[e] = (_Float16)(v[e]*inv); ob[e] = (_Float16)(v[8+e]*inv); }
  ((half8*)p)[t*2]     = oa;
  ((half8*)p)[t*2 + 1] = ob;
}

// ======== exact top-k (4x8-bit radix on f32 keys) + masked softmax, f16 in place ========
__global__ __launch_bounds__(256) void sparse_softmax_inplace(float* __restrict__ sc, int ksel){
  __shared__ unsigned hist[256];
  __shared__ unsigned suf[256];
  __shared__ int selb;
  __shared__ float red[4], red2[4];
  const int t = threadIdx.x, lane = t & 63, wid = t >> 6;
  float* p = sc + (size_t)blockIdx.x * 4096;
  float v[16]; unsigned kk[16];
  #pragma unroll
  for (int j = 0; j < 4; j++){
    float4 q = *(const float4*)(p + t*16 + j*4);
    v[4*j] = q.x; v[4*j+1] = q.y; v[4*j+2] = q.z; v[4*j+3] = q.w;
  }
  #pragma unroll
  for (int e = 0; e < 16; e++) kk[e] = f2k(v[e]);
  float m = v[0];
  #pragma unroll
  for (int e = 1; e < 16; e++) m = fmaxf(m, v[e]);
  m = wred_max(m);
  if (lane == 0) red[wid] = m;
  __syncthreads();
  m = fmaxf(fmaxf(red[0], red[1]), fmaxf(red[2], red[3]));

  unsigned prefix = 0;
  unsigned remaining = (unsigned)ksel;
  for (int pass = 0; pass < 4; ++pass){
    const int shift = 24 - 8*pass;
    hist[t] = 0u;
    __syncthreads();
    #pragma unroll
    for (int e = 0; e < 16; e++){
      unsigned k = kk[e];
      bool cand = (pass == 0) || ((k >> (shift + 8)) == prefix);
      if (cand) atomicAdd(&hist[(k >> shift) & 255u], 1u);
    }
    __syncthreads();
    suf[t] = hist[t];
    __syncthreads();
    for (int off = 1; off < 256; off <<= 1){
      unsigned add = (t + off < 256) ? suf[t + off] : 0u;
      __syncthreads();
      suf[t] += add;
      __syncthreads();
    }
    if (suf[t] >= remaining && (t == 255 || suf[t+1] < remaining)) selb = t;
    __syncthreads();
    int b = selb;
    remaining -= (b == 255) ? 0u : suf[b+1];
    prefix = (prefix << 8) | (unsigned)b;
    __syncthreads();
  }
  const unsigned Tkey = prefix;

  float ev[16];
  float s = 0.f;
  #pragma unroll
  for (int e = 0; e < 16; e++){
    ev[e] = (kk[e] >= Tkey) ? expf(v[e] - m) : 0.f;
    s += ev[e];
  }
  s = wred_sum(s);
  if (lane == 0) red2[wid] = s;
  __syncthreads();
  s = red2[0] + red2[1] + red2[2] + red2[3];
  const float inv = 1.0f / s;
  _Float16* ph = (_Float16*)p;
  half8 o0, o1;
  #pragma unroll
  for (int e = 0; e < 8; e++){
    o0[e] = (_Float16)(ev[e]   * inv);
    o1[e] = (_Float16)(ev[8+e] * inv);
  }
  *(half8*)(ph + t*16)     = o0;
  *(half8*)(ph + t*16 + 8) = o1;
}

// ======== memory-head softmax over 64 scores: one wave per row ========
__global__ __launch_bounds__(256) void msoftmax64(const float* __restrict__ mscore,
                                                  _Float16* __restrict__ mprob){
  const int t = threadIdx.x, lane = t & 63, wid = t >> 6;
  const size_t row = (size_t)blockIdx.x * 4 + wid;
  float v = mscore[row*64 + lane];
  float m = wred_max(v);
  float e = expf(v - m);
  float s = wred_sum(e);
  mprob[row*64 + lane] = (_Float16)(e / s);
}

extern "C" void kernel_launch(void* const* d_in, const int* in_sizes, int n_in,
                              void* d_out, int out_size, void* d_ws, size_t ws_size,
                              hipStream_t stream)
{
  const float* x             = (const float*)d_in[0];
  const float* local_qkv_w   = (const float*)d_in[1];
  const float* sparse_qkv_w  = (const float*)d_in[2];
  const float* memory_bank   = (const float*)d_in[3];
  const float* memory_proj_w = (const float*)d_in[4];
  const float* mem_out_w     = (const float*)d_in[5];
  const float* mem_out_b     = (const float*)d_in[6];
  const float* pred_in_w     = (const float*)d_in[7];
  const float* pred_in_b     = (const float*)d_in[8];
  const float* pred1_w       = (const float*)d_in[9];
  const float* pred1_b       = (const float*)d_in[10];
  const float* pred2_w       = (const float*)d_in[11];
  const float* pred2_b       = (const float*)d_in[12];
  const float* warboss_w     = (const float*)d_in[13];
  const float* warboss_b     = (const float*)d_in[14];
  float* out = (float*)d_out;

  // ---- workspace layout (bytes).
  // Region A [0, 67,108,864): per-phase —
  //   early scratch: x_h [0,16.8M) | mem_cat [16.8M,25.2M) | h_in [25.2M,29.4M)
  //                  | h1 [29.4M,37.75M) | mscore [37.75M,39.85M) | mprob [39.85M,40.9M)
  //   local phase:  f16 scores/probs [2][4096][4096]
  //   sparse phase: f32 scores [4096][4096] (one batch at a time)
  char* wsb = (char*)d_ws;
  _Float16*  scores_h = (_Float16*)wsb;
  float*     scores_f = (float*)wsb;
  _Float16*  x_h      = (_Float16*)wsb;
  _Float16*  mem_cat  = (_Float16*)(wsb + 16777216);
  _Float16*  h_in     = (_Float16*)(wsb + 25165824);
  _Float16*  h1       = (_Float16*)(wsb + 29360128);
  float*     mscore   = (float*)(wsb + 37748736);
  _Float16*  mprob    = (_Float16*)(wsb + 39845888);
  _Float16*  qkv_l    = (_Float16*)(wsb + 67108864);   // [8192][768]
  _Float16*  qkv_s    = (_Float16*)(wsb + 79691776);   // [8192][768]
  _Float16*  Vt       = (_Float16*)(wsb + 92274688);   // [2][256][4096]
  _Float16*  comb     = (_Float16*)(wsb + 96468992);   // [8192][1024]
  _Float16*  lqkvT    = (_Float16*)(wsb + 113246208);  // [768][1024]
  _Float16*  sqkvT    = lqkvT  + 786432;
  _Float16*  mprojT   = sqkvT  + 786432;               // [256][1024]
  _Float16*  moutT    = mprojT + 262144;               // [256][512]
  _Float16*  pinT     = moutT  + 131072;               // [256][1024]
  _Float16*  p1T      = pinT   + 262144;               // [512][256]
  _Float16*  p2T      = p1T    + 131072;               // [256][512]
  _Float16*  wbT      = p2T    + 131072;               // [1024][1024]
  _Float16*  bank_h   = wbT    + 1048576;              // [64][256]
  _Float16*  bankT_h  = bank_h + 16384;                // [256][64]

  const dim3 blk(256);
  const float scale = 0.0625f;
  const long QZ  = (long)4096 * 768;
  const long VZ  = (long)256 * 4096;
  const long CZ  = (long)4096 * 1024;
  const long SZH = (long)4096 * 4096;   // f16 scores z-stride (elements)

  // ---- casts / weight transposes ----
  cast_xh<<<dim3(2048), blk, 0, stream>>>(x, x_h, 1048576);
  cast_xh<<<dim3(8), blk, 0, stream>>>(memory_bank, bank_h, 2048);
  transpose_cast_w<<<dim3(24,32), blk, 0, stream>>>(local_qkv_w,  1024,  768, lqkvT);
  transpose_cast_w<<<dim3(24,32), blk, 0, stream>>>(sparse_qkv_w, 1024,  768, sqkvT);
  transpose_cast_w<<<dim3( 8,32), blk, 0, stream>>>(memory_proj_w,1024,  256, mprojT);
  transpose_cast_w<<<dim3( 8,16), blk, 0, stream>>>(mem_out_w,     512,  256, moutT);
  transpose_cast_w<<<dim3( 8,32), blk, 0, stream>>>(pred_in_w,    1024,  256, pinT);
  transpose_cast_w<<<dim3(16, 8), blk, 0, stream>>>(pred1_w,       256,  512, p1T);
  transpose_cast_w<<<dim3( 8,16), blk, 0, stream>>>(pred2_w,       512,  256, p2T);
  transpose_cast_w<<<dim3(32,32), blk, 0, stream>>>(warboss_w,    1024, 1024, wbT);
  transpose_cast_w<<<dim3( 8, 2), blk, 0, stream>>>(memory_bank,    64,  256, bankT_h);

  // ---- QKV projections ----
  gemm_ht<128,128,1,0><<<dim3(6,64), blk, 0, stream>>>(x_h,0,1024, lqkvT,0,1024, qkv_l,0,768, 1024, 1.f, nullptr);
  gemm_ht<128,128,1,0><<<dim3(6,64), blk, 0, stream>>>(x_h,0,1024, sqkvT,0,1024, qkv_s,0,768, 1024, 1.f, nullptr);

  // ---- memory head (GEMM chain) -> comb[:, 512:768] ----
  gemm_ht<128,64,1,0><<<dim3(4,64), blk, 0, stream>>>(x_h,0,1024, mprojT,0,1024, mem_cat,0,512, 1024, 1.f, nullptr);
  gemm_ht<128,64,0,0><<<dim3(1,64), blk, 0, stream>>>(mem_cat,0,512, bank_h,0,256, (void*)mscore,0,64, 256, 1.f, nullptr);
  msoftmax64<<<dim3(2048), blk, 0, stream>>>(mscore, mprob);
  gemm_ht<128,64,1,0><<<dim3(4,64), blk, 0, stream>>>(mprob,0,64, bankT_h,0,64, mem_cat+256,0,512, 64, 1.f, nullptr);
  gemm_ht<128,64,1,0><<<dim3(4,64), blk, 0, stream>>>(mem_cat,0,512, moutT,0,512, comb+512,0,1024, 512, 1.f, mem_out_b);

  // ---- prediction head -> comb[:, 768:1024] ----
  gemm_ht<128,64,1,0><<<dim3(4,64), blk, 0, stream>>>(x_h,0,1024, pinT,0,1024, h_in,0,256, 1024, 1.f, pred_in_b);
  gemm_ht<128,128,1,1><<<dim3(4,64), blk, 0, stream>>>(h_in,0,256, p1T,0,256, h1,0,512, 256, 1.f, pred1_b);
  gemm_ht<128,64,1,0><<<dim3(4,64), blk, 0, stream>>>(h1,0,512, p2T,0,512, comb+768,0,1024, 512, 1.f, pred2_b);

  // ---- local (full) attention -> comb[:, 0:256]; f16 scores, z-batched ----
  transpose_h<<<dim3(8,128,2), blk, 0, stream>>>(qkv_l+512, QZ, 768, Vt, VZ, 4096);
  gemm_ht<128,128,1,0><<<dim3(32,32,2), blk, 0, stream>>>(qkv_l,QZ,768, qkv_l+256,QZ,768,
                                                          (void*)scores_h,SZH,4096, 256, scale, nullptr);
  softmax_f16row<<<dim3(8192), blk, 0, stream>>>(scores_h);
  gemm_pv<128,64><<<dim3(4,32,8), blk, 0, stream>>>(scores_h,SZH,4096, Vt,VZ,4096, out, 4, 1024);
  reduce4<<<dim3(2048), blk, 0, stream>>>(out, comb, 0, 524288);

  // ---- sparse (top-k) attention -> comb[:, 256:512]; f32 scores per batch ----
  transpose_h<<<dim3(8,128,2), blk, 0, stream>>>(qkv_s+512, QZ, 768, Vt, VZ, 4096);
  for (int b = 0; b < 2; b++){
    const _Float16* Q = qkv_s + (long)b * QZ;
    gemm_ht<128,128,0,0><<<dim3(32,32), blk, 0, stream>>>(Q,0,768, Q+256,0,768, (void*)scores_f,0,4096, 256, scale, nullptr);
    sparse_softmax_inplace<<<dim3(4096), blk, 0, stream>>>(scores_f, 409);
    gemm_pv<128,64><<<dim3(4,32,4), blk, 0, stream>>>((const _Float16*)scores_f,0,8192, Vt + (long)b*VZ,0,4096, out, 4, 1024);
    reduce4<<<dim3(1024), blk, 0, stream>>>(out, comb + (long)b*CZ, 256, 262144);
  }

  // ---- output projection (f32 out) ----
  gemm_ht<128,128,0,0><<<dim3(8,64), blk, 0, stream>>>(comb,0,1024, wbT,0,1024, (void*)out,0,1024, 1024, 1.f, warboss_b);
}

// Round 5
// 553.287 us; speedup vs baseline: 4.6742x; 1.0203x over previous
//
#include <hip/hip_runtime.h>
#include <hip/hip_bf16.h>

typedef __attribute__((ext_vector_type(8))) _Float16 half8;
typedef __attribute__((ext_vector_type(4))) _Float16 half4v;
typedef __attribute__((ext_vector_type(4))) float f32x4;

__device__ __forceinline__ float wred_max(float v){
  #pragma unroll
  for (int o = 32; o; o >>= 1) v = fmaxf(v, __shfl_xor(v, o));
  return v;
}
__device__ __forceinline__ float wred_sum(float v){
  #pragma unroll
  for (int o = 32; o; o >>= 1) v += __shfl_xor(v, o);
  return v;
}
__device__ __forceinline__ unsigned f2k(float f){
  unsigned u = __float_as_uint(f);
  return (u & 0x80000000u) ? ~u : (u | 0x80000000u);
}

#define GLOAD16(GP, LP) __builtin_amdgcn_global_load_lds( \
    (const __attribute__((address_space(1))) void*)(GP),  \
    (__attribute__((address_space(3))) void*)(LP), 16, 0, 0)

// ======== MFMA GEMM (f16 in, f32 acc): C = alpha * A(MxK) @ B(NxK)^T (+bias) ========
// z-batched via saz/sbz/scz element strides. OUT_F16: 1 -> f16 C, 0 -> f32 C. ACT=1 -> exact GELU.
template<int BM, int BN, int OUT_F16, int ACT>
__global__ __launch_bounds__(256) void gemm_ht(
    const _Float16* __restrict__ A, long saz, int lda,
    const _Float16* __restrict__ B, long sbz, int ldb,
    void* __restrict__ Cv, long scz, int ldc,
    int K, float alpha, const float* __restrict__ bias)
{
  constexpr int FM = BM / 32, FN = BN / 32;
  __shared__ __align__(16) _Float16 Asl[BM * 32];
  __shared__ __align__(16) _Float16 Bsl[BN * 32];
  const int t = threadIdx.x;
  const int wid = t >> 6, lane = t & 63;
  const int wr = wid >> 1, wc = wid & 1;
  const int lr = lane & 15, kg = lane >> 4;
  A += (long)blockIdx.z * saz;
  B += (long)blockIdx.z * sbz;
  const long row0 = (long)blockIdx.y * BM;
  const long col0 = (long)blockIdx.x * BN;

  f32x4 acc[FM][FN];
  #pragma unroll
  for (int i = 0; i < FM; i++)
    #pragma unroll
    for (int j = 0; j < FN; j++)
      acc[i][j] = (f32x4){0.f, 0.f, 0.f, 0.f};

  const int arow_t = t >> 2, acol_t = (t & 3) * 8;

  for (int k0 = 0; k0 < K; k0 += 32){
    #pragma unroll
    for (int r = 0; r < BM / 64; r++){
      const _Float16* gp = A + (row0 + r*64 + arow_t) * (long)lda + k0 + acol_t;
      GLOAD16(gp, (char*)Asl + r*4096 + wid*1024);
    }
    #pragma unroll
    for (int r = 0; r < BN / 64; r++){
      const _Float16* gp = B + (col0 + r*64 + arow_t) * (long)ldb + k0 + acol_t;
      GLOAD16(gp, (char*)Bsl + r*4096 + wid*1024);
    }
    __syncthreads();
    half8 af[FM], bfv[FN];
    #pragma unroll
    for (int i = 0; i < FM; i++)
      af[i] = *(const half8*)((const char*)Asl + (wr*(BM/2) + i*16 + lr)*64 + kg*16);
    #pragma unroll
    for (int j = 0; j < FN; j++)
      bfv[j] = *(const half8*)((const char*)Bsl + (wc*(BN/2) + j*16 + lr)*64 + kg*16);
    #pragma unroll
    for (int i = 0; i < FM; i++)
      #pragma unroll
      for (int j = 0; j < FN; j++)
        acc[i][j] = __builtin_amdgcn_mfma_f32_16x16x32_f16(af[i], bfv[j], acc[i][j], 0, 0, 0);
    __syncthreads();
  }

  _Float16* Ch = (_Float16*)Cv + (long)blockIdx.z * scz;
  float*    Cf = (float*)Cv    + (long)blockIdx.z * scz;
  #pragma unroll
  for (int i = 0; i < FM; i++){
    #pragma unroll
    for (int j = 0; j < FN; j++){
      #pragma unroll
      for (int q = 0; q < 4; q++){
        long rr = row0 + wr*(BM/2) + i*16 + kg*4 + q;
        long cc = col0 + wc*(BN/2) + j*16 + lr;
        float val = acc[i][j][q] * alpha;
        if (bias) val += bias[cc];
        if constexpr (ACT) val = 0.5f * val * (1.0f + erff(val * 0.70710678118654752f));
        if constexpr (OUT_F16) Ch[rr*(long)ldc + cc] = (_Float16)val;
        else                   Cf[rr*(long)ldc + cc] = val;
      }
    }
  }
}

// ======== split-K PV GEMM, BN=256 (full width, A read once): f32 partials ========
// z = batch*nsplit + split; partial block z at P + z*4096*256. grid (1, 4096/BM, z).
template<int BM, int BN>
__global__ __launch_bounds__(256) void gemm_pv(
    const _Float16* __restrict__ A, long saz, int lda,
    const _Float16* __restrict__ B, long sbz, int ldb,
    float* __restrict__ P, int nsplit, int Ksplit)
{
  constexpr int FM = BM / 32, FN = BN / 32;
  __shared__ __align__(16) _Float16 Asl[BM * 32];
  __shared__ __align__(16) _Float16 Bsl[BN * 32];
  const int t = threadIdx.x;
  const int wid = t >> 6, lane = t & 63;
  const int wr = wid >> 1, wc = wid & 1;
  const int lr = lane & 15, kg = lane >> 4;
  const int z = blockIdx.z, batch = z / nsplit, split = z % nsplit;
  A += (long)batch * saz;
  B += (long)batch * sbz;
  float* Pz = P + (size_t)z * (4096 * 256);
  const long row0 = (long)blockIdx.y * BM;
  const int Kbase = split * Ksplit;

  f32x4 acc[FM][FN];
  #pragma unroll
  for (int i = 0; i < FM; i++)
    #pragma unroll
    for (int j = 0; j < FN; j++)
      acc[i][j] = (f32x4){0.f, 0.f, 0.f, 0.f};

  const int arow_t = t >> 2, acol_t = (t & 3) * 8;

  for (int k0 = 0; k0 < Ksplit; k0 += 32){
    #pragma unroll
    for (int r = 0; r < BM / 64; r++){
      const _Float16* gp = A + (row0 + r*64 + arow_t) * (long)lda + Kbase + k0 + acol_t;
      GLOAD16(gp, (char*)Asl + r*4096 + wid*1024);
    }
    #pragma unroll
    for (int r = 0; r < BN / 64; r++){
      const _Float16* gp = B + (r*64 + arow_t) * (long)ldb + Kbase + k0 + acol_t;
      GLOAD16(gp, (char*)Bsl + r*4096 + wid*1024);
    }
    __syncthreads();
    half8 af[FM], bfv[FN];
    #pragma unroll
    for (int i = 0; i < FM; i++)
      af[i] = *(const half8*)((const char*)Asl + (wr*(BM/2) + i*16 + lr)*64 + kg*16);
    #pragma unroll
    for (int j = 0; j < FN; j++)
      bfv[j] = *(const half8*)((const char*)Bsl + (wc*(BN/2) + j*16 + lr)*64 + kg*16);
    #pragma unroll
    for (int i = 0; i < FM; i++)
      #pragma unroll
      for (int j = 0; j < FN; j++)
        acc[i][j] = __builtin_amdgcn_mfma_f32_16x16x32_f16(af[i], bfv[j], acc[i][j], 0, 0, 0);
    __syncthreads();
  }

  #pragma unroll
  for (int i = 0; i < FM; i++)
    #pragma unroll
    for (int j = 0; j < FN; j++)
      #pragma unroll
      for (int q = 0; q < 4; q++){
        long rr = row0 + wr*(BM/2) + i*16 + kg*4 + q;
        long cc = wc*(BN/2) + j*16 + lr;
        Pz[rr*256 + cc] = acc[i][j][q];
      }
}

// ======== sum 4 split-K partials -> f16 into comb at column offset ========
__global__ __launch_bounds__(256) void reduce4(const float* __restrict__ P,
                                               _Float16* __restrict__ dst, int coff, int nq){
  int i = blockIdx.x * 256 + threadIdx.x;
  if (i >= nq) return;
  int b = i >> 18;
  int r = i & 262143;
  int row = r >> 6, col4 = r & 63;
  const float4* P4 = (const float4*)P;
  float4 s = P4[(size_t)(b*4 + 0) * 262144 + r];
  #pragma unroll
  for (int sp = 1; sp < 4; sp++){
    float4 q = P4[(size_t)(b*4 + sp) * 262144 + r];
    s.x += q.x; s.y += q.y; s.z += q.z; s.w += q.w;
  }
  half4v o;
  o[0] = (_Float16)s.x; o[1] = (_Float16)s.y; o[2] = (_Float16)s.z; o[3] = (_Float16)s.w;
  *(half4v*)(dst + ((size_t)b*4096 + row)*1024 + coff + col4*4) = o;
}

// ======== cast f32 -> f16 (8 elems/thread) ========
__global__ __launch_bounds__(256) void cast_xh(const float* __restrict__ in,
                                               _Float16* __restrict__ out, int n8){
  int i = blockIdx.x * 256 + threadIdx.x;
  const int stride = gridDim.x * 256;
  for (; i < n8; i += stride){
    float4 a = ((const float4*)in)[2*i];
    float4 b = ((const float4*)in)[2*i + 1];
    half8 o;
    o[0]=(_Float16)a.x; o[1]=(_Float16)a.y; o[2]=(_Float16)a.z; o[3]=(_Float16)a.w;
    o[4]=(_Float16)b.x; o[5]=(_Float16)b.y; o[6]=(_Float16)b.z; o[7]=(_Float16)b.w;
    *(half8*)(out + (size_t)i*8) = o;
  }
}

// ======== transpose+cast weight: in (R x C) f32 -> out (C x R) f16 ========
__global__ __launch_bounds__(256) void transpose_cast_w(const float* __restrict__ in, int R, int C,
                                                        _Float16* __restrict__ out){
  __shared__ float tile[32][33];
  const int c0 = blockIdx.x * 32, r0 = blockIdx.y * 32;
  const int tx = threadIdx.x & 31, ty = threadIdx.x >> 5;
  #pragma unroll
  for (int i = 0; i < 32; i += 8)
    tile[ty+i][tx] = in[(size_t)(r0+ty+i)*C + c0+tx];
  __syncthreads();
  #pragma unroll
  for (int i = 0; i < 32; i += 8)
    out[(size_t)(c0+ty+i)*R + r0+tx] = (_Float16)tile[tx][ty+i];
}

// ======== f16 transpose: in (R x C, ld_in) -> out (C x R, ld_out), z-batched ========
__global__ __launch_bounds__(256) void transpose_h(
    const _Float16* __restrict__ in, long in_z, int ld_in,
    _Float16* __restrict__ out, long out_z, int ld_out)
{
  __shared__ _Float16 tile[32][34];
  const _Float16* ip = in + (long)blockIdx.z * in_z;
  _Float16* op = out + (long)blockIdx.z * out_z;
  const int c0 = blockIdx.x * 32, r0 = blockIdx.y * 32;
  const int tx = threadIdx.x & 31, ty = threadIdx.x >> 5;
  #pragma unroll
  for (int i = 0; i < 32; i += 8)
    tile[ty+i][tx] = ip[(long)(r0+ty+i)*ld_in + c0+tx];
  __syncthreads();
  #pragma unroll
  for (int i = 0; i < 32; i += 8)
    op[(long)(c0+ty+i)*ld_out + r0+tx] = tile[tx][ty+i];
}

// ======== full softmax over a 4096-wide f16 row, in place (local head) ========
__global__ __launch_bounds__(256) void softmax_f16row(_Float16* __restrict__ sc){
  __shared__ float red[4], red2[4];
  const int t = threadIdx.x, lane = t & 63, wid = t >> 6;
  _Float16* p = sc + (size_t)blockIdx.x * 4096;
  half8 a = ((const half8*)p)[t*2];
  half8 b = ((const half8*)p)[t*2 + 1];
  float v[16];
  #pragma unroll
  for (int e = 0; e < 8; e++){ v[e] = (float)a[e]; v[8+e] = (float)b[e]; }
  float m = v[0];
  #pragma unroll
  for (int e = 1; e < 16; e++) m = fmaxf(m, v[e]);
  m = wred_max(m);
  if (lane == 0) red[wid] = m;
  __syncthreads();
  m = fmaxf(fmaxf(red[0], red[1]), fmaxf(red[2], red[3]));
  float s = 0.f;
  #pragma unroll
  for (int e = 0; e < 16; e++){ v[e] = expf(v[e] - m); s += v[e]; }
  s = wred_sum(s);
  if (lane == 0) red2[wid] = s;
  __syncthreads();
  s = red2[0] + red2[1] + red2[2] + red2[3];
  const float inv = 1.0f / s;
  half8 oa, ob;
  #pragma unroll
  for (int e = 0; e < 8; e++){ oa[e] = (_Float16)(v[e]*inv); ob[e] = (_Float16)(v[8+e]*inv); }
  ((half8*)p)[t*2]     = oa;
  ((half8*)p)[t*2 + 1] = ob;
}

// ======== exact top-k (4x8-bit radix on f32 keys) + masked softmax, f16 in place ========
__global__ __launch_bounds__(256) void sparse_softmax_inplace(float* __restrict__ sc, int ksel){
  __shared__ unsigned hist[256];
  __shared__ unsigned suf[256];
  __shared__ int selb;
  __shared__ float red[4], red2[4];
  const int t = threadIdx.x, lane = t & 63, wid = t >> 6;
  float* p = sc + (size_t)blockIdx.x * 4096;
  float v[16]; unsigned kk[16];
  #pragma unroll
  for (int j = 0; j < 4; j++){
    float4 q = *(const float4*)(p + t*16 + j*4);
    v[4*j] = q.x; v[4*j+1] = q.y; v[4*j+2] = q.z; v[4*j+3] = q.w;
  }
  #pragma unroll
  for (int e = 0; e < 16; e++) kk[e] = f2k(v[e]);
  float m = v[0];
  #pragma unroll
  for (int e = 1; e < 16; e++) m = fmaxf(m, v[e]);
  m = wred_max(m);
  if (lane == 0) red[wid] = m;
  __syncthreads();
  m = fmaxf(fmaxf(red[0], red[1]), fmaxf(red[2], red[3]));

  unsigned prefix = 0;
  unsigned remaining = (unsigned)ksel;
  for (int pass = 0; pass < 4; ++pass){
    const int shift = 24 - 8*pass;
    hist[t] = 0u;
    __syncthreads();
    #pragma unroll
    for (int e = 0; e < 16; e++){
      unsigned k = kk[e];
      bool cand = (pass == 0) || ((k >> (shift + 8)) == prefix);
      if (cand) atomicAdd(&hist[(k >> shift) & 255u], 1u);
    }
    __syncthreads();
    suf[t] = hist[t];
    __syncthreads();
    for (int off = 1; off < 256; off <<= 1){
      unsigned add = (t + off < 256) ? suf[t + off] : 0u;
      __syncthreads();
      suf[t] += add;
      __syncthreads();
    }
    if (suf[t] >= remaining && (t == 255 || suf[t+1] < remaining)) selb = t;
    __syncthreads();
    int b = selb;
    remaining -= (b == 255) ? 0u : suf[b+1];
    prefix = (prefix << 8) | (unsigned)b;
    __syncthreads();
  }
  const unsigned Tkey = prefix;

  float ev[16];
  float s = 0.f;
  #pragma unroll
  for (int e = 0; e < 16; e++){
    ev[e] = (kk[e] >= Tkey) ? expf(v[e] - m) : 0.f;
    s += ev[e];
  }
  s = wred_sum(s);
  if (lane == 0) red2[wid] = s;
  __syncthreads();
  s = red2[0] + red2[1] + red2[2] + red2[3];
  const float inv = 1.0f / s;
  _Float16* ph = (_Float16*)p;
  half8 o0, o1;
  #pragma unroll
  for (int e = 0; e < 8; e++){
    o0[e] = (_Float16)(ev[e]   * inv);
    o1[e] = (_Float16)(ev[8+e] * inv);
  }
  *(half8*)(ph + t*16)     = o0;
  *(half8*)(ph + t*16 + 8) = o1;
}

// ======== memory-head softmax over 64 scores: one wave per row ========
__global__ __launch_bounds__(256) void msoftmax64(const float* __restrict__ mscore,
                                                  _Float16* __restrict__ mprob){
  const int t = threadIdx.x, lane = t & 63, wid = t >> 6;
  const size_t row = (size_t)blockIdx.x * 4 + wid;
  float v = mscore[row*64 + lane];
  float m = wred_max(v);
  float e = expf(v - m);
  float s = wred_sum(e);
  mprob[row*64 + lane] = (_Float16)(e / s);
}

extern "C" void kernel_launch(void* const* d_in, const int* in_sizes, int n_in,
                              void* d_out, int out_size, void* d_ws, size_t ws_size,
                              hipStream_t stream)
{
  const float* x             = (const float*)d_in[0];
  const float* local_qkv_w   = (const float*)d_in[1];
  const float* sparse_qkv_w  = (const float*)d_in[2];
  const float* memory_bank   = (const float*)d_in[3];
  const float* memory_proj_w = (const float*)d_in[4];
  const float* mem_out_w     = (const float*)d_in[5];
  const float* mem_out_b     = (const float*)d_in[6];
  const float* pred_in_w     = (const float*)d_in[7];
  const float* pred_in_b     = (const float*)d_in[8];
  const float* pred1_w       = (const float*)d_in[9];
  const float* pred1_b       = (const float*)d_in[10];
  const float* pred2_w       = (const float*)d_in[11];
  const float* pred2_b       = (const float*)d_in[12];
  const float* warboss_w     = (const float*)d_in[13];
  const float* warboss_b     = (const float*)d_in[14];
  float* out = (float*)d_out;

  char* wsb = (char*)d_ws;
  _Float16*  scores_h = (_Float16*)wsb;
  float*     scores_f = (float*)wsb;
  _Float16*  x_h      = (_Float16*)wsb;
  _Float16*  mem_cat  = (_Float16*)(wsb + 16777216);
  _Float16*  h_in     = (_Float16*)(wsb + 25165824);
  _Float16*  h1       = (_Float16*)(wsb + 29360128);
  float*     mscore   = (float*)(wsb + 37748736);
  _Float16*  mprob    = (_Float16*)(wsb + 39845888);
  _Float16*  qkv_l    = (_Float16*)(wsb + 67108864);   // [8192][768]
  _Float16*  qkv_s    = (_Float16*)(wsb + 79691776);   // [8192][768]
  _Float16*  Vt       = (_Float16*)(wsb + 92274688);   // [2][256][4096]
  _Float16*  comb     = (_Float16*)(wsb + 96468992);   // [8192][1024]
  _Float16*  lqkvT    = (_Float16*)(wsb + 113246208);  // [768][1024]
  _Float16*  sqkvT    = lqkvT  + 786432;
  _Float16*  mprojT   = sqkvT  + 786432;               // [256][1024]
  _Float16*  moutT    = mprojT + 262144;               // [256][512]
  _Float16*  pinT     = moutT  + 131072;               // [256][1024]
  _Float16*  p1T      = pinT   + 262144;               // [512][256]
  _Float16*  p2T      = p1T    + 131072;               // [256][512]
  _Float16*  wbT      = p2T    + 131072;               // [1024][1024]
  _Float16*  bank_h   = wbT    + 1048576;              // [64][256]
  _Float16*  bankT_h  = bank_h + 16384;                // [256][64]

  const dim3 blk(256);
  const float scale = 0.0625f;
  const long QZ  = (long)4096 * 768;
  const long VZ  = (long)256 * 4096;
  const long CZ  = (long)4096 * 1024;
  const long SZH = (long)4096 * 4096;

  // ---- casts / weight transposes ----
  cast_xh<<<dim3(2048), blk, 0, stream>>>(x, x_h, 1048576);
  cast_xh<<<dim3(8), blk, 0, stream>>>(memory_bank, bank_h, 2048);
  transpose_cast_w<<<dim3(24,32), blk, 0, stream>>>(local_qkv_w,  1024,  768, lqkvT);
  transpose_cast_w<<<dim3(24,32), blk, 0, stream>>>(sparse_qkv_w, 1024,  768, sqkvT);
  transpose_cast_w<<<dim3( 8,32), blk, 0, stream>>>(memory_proj_w,1024,  256, mprojT);
  transpose_cast_w<<<dim3( 8,16), blk, 0, stream>>>(mem_out_w,     512,  256, moutT);
  transpose_cast_w<<<dim3( 8,32), blk, 0, stream>>>(pred_in_w,    1024,  256, pinT);
  transpose_cast_w<<<dim3(16, 8), blk, 0, stream>>>(pred1_w,       256,  512, p1T);
  transpose_cast_w<<<dim3( 8,16), blk, 0, stream>>>(pred2_w,       512,  256, p2T);
  transpose_cast_w<<<dim3(32,32), blk, 0, stream>>>(warboss_w,    1024, 1024, wbT);
  transpose_cast_w<<<dim3( 8, 2), blk, 0, stream>>>(memory_bank,    64,  256, bankT_h);

  // ---- QKV projections ----
  gemm_ht<128,128,1,0><<<dim3(6,64), blk, 0, stream>>>(x_h,0,1024, lqkvT,0,1024, qkv_l,0,768, 1024, 1.f, nullptr);
  gemm_ht<128,128,1,0><<<dim3(6,64), blk, 0, stream>>>(x_h,0,1024, sqkvT,0,1024, qkv_s,0,768, 1024, 1.f, nullptr);

  // ---- memory head (GEMM chain) -> comb[:, 512:768] ----
  gemm_ht<128,64,1,0><<<dim3(4,64), blk, 0, stream>>>(x_h,0,1024, mprojT,0,1024, mem_cat,0,512, 1024, 1.f, nullptr);
  gemm_ht<128,64,0,0><<<dim3(1,64), blk, 0, stream>>>(mem_cat,0,512, bank_h,0,256, (void*)mscore,0,64, 256, 1.f, nullptr);
  msoftmax64<<<dim3(2048), blk, 0, stream>>>(mscore, mprob);
  gemm_ht<128,64,1,0><<<dim3(4,64), blk, 0, stream>>>(mprob,0,64, bankT_h,0,64, mem_cat+256,0,512, 64, 1.f, nullptr);
  gemm_ht<128,64,1,0><<<dim3(4,64), blk, 0, stream>>>(mem_cat,0,512, moutT,0,512, comb+512,0,1024, 512, 1.f, mem_out_b);

  // ---- prediction head -> comb[:, 768:1024] ----
  gemm_ht<128,64,1,0><<<dim3(4,64), blk, 0, stream>>>(x_h,0,1024, pinT,0,1024, h_in,0,256, 1024, 1.f, pred_in_b);
  gemm_ht<128,128,1,1><<<dim3(4,64), blk, 0, stream>>>(h_in,0,256, p1T,0,256, h1,0,512, 256, 1.f, pred1_b);
  gemm_ht<128,64,1,0><<<dim3(4,64), blk, 0, stream>>>(h1,0,512, p2T,0,512, comb+768,0,1024, 512, 1.f, pred2_b);

  // ---- local (full) attention -> comb[:, 0:256]; f16 scores, z-batched ----
  transpose_h<<<dim3(8,128,2), blk, 0, stream>>>(qkv_l+512, QZ, 768, Vt, VZ, 4096);
  gemm_ht<128,128,1,0><<<dim3(32,32,2), blk, 0, stream>>>(qkv_l,QZ,768, qkv_l+256,QZ,768,
                                                          (void*)scores_h,SZH,4096, 256, scale, nullptr);
  softmax_f16row<<<dim3(8192), blk, 0, stream>>>(scores_h);
  gemm_pv<64,256><<<dim3(1,64,8), blk, 0, stream>>>(scores_h,SZH,4096, Vt,VZ,4096, out, 4, 1024);
  reduce4<<<dim3(2048), blk, 0, stream>>>(out, comb, 0, 524288);

  // ---- sparse (top-k) attention -> comb[:, 256:512]; f32 scores per batch ----
  transpose_h<<<dim3(8,128,2), blk, 0, stream>>>(qkv_s+512, QZ, 768, Vt, VZ, 4096);
  for (int b = 0; b < 2; b++){
    const _Float16* Q = qkv_s + (long)b * QZ;
    gemm_ht<128,128,0,0><<<dim3(32,32), blk, 0, stream>>>(Q,0,768, Q+256,0,768, (void*)scores_f,0,4096, 256, scale, nullptr);
    sparse_softmax_inplace<<<dim3(4096), blk, 0, stream>>>(scores_f, 409);
    gemm_pv<64,256><<<dim3(1,64,4), blk, 0, stream>>>((const _Float16*)scores_f,0,8192, Vt + (long)b*VZ,0,4096, out, 4, 1024);
    reduce4<<<dim3(1024), blk, 0, stream>>>(out, comb + (long)b*CZ, 256, 262144);
  }

  // ---- output projection (f32 out) ----
  gemm_ht<128,128,0,0><<<dim3(8,64), blk, 0, stream>>>(comb,0,1024, wbT,0,1024, (void*)out,0,1024, 1024, 1.f, warboss_b);
}